// Round 2
// baseline (793.258 us; speedup 1.0000x reference)
//
#include <hip/hip_runtime.h>

// VolumeRotation direct-gather: B=8, C=16, S=64.
//
// R2: drop LDS staging entirely. Post-swizzle rocprof showed FETCH ~= one
// pass over the volume (119 MB vs 128 MB volume) -> the per-tile region is
// L2/L1-resident, so staging it through LDS (16 gl + 16 ds_write + 8
// ds_read2 per wave-channel, 2 barriers/channel) was pure overhead
// (common-mistake #7). Now each point precomputes its 8 clamped tap
// offsets + 8 validity-folded trilinear weights ONCE, then the channel
// loop is 8 saddr-form global loads + 8 FMA + 1 store per point.
// No barriers, no LDS -> 32 waves/CU run free, TLP hides gather latency.
//
// Kept from R1: XCD-contiguous block swizzle (2048 blocks / 8 XCDs = 256
// = exactly one batch per XCD -> channel slice stays in that XCD's L2).
// Reverted from R1: all break-guarded loops (they sent arrays to scratch,
// VGPR 48->36 + 14 MB scratch writes, dur 208->306 us).

#define S 64
#define SP (S * S * S)
#define CCH 16
#define BB 8

#define TW 16
#define TH 8
#define TD 8
#define NT 512           // threads per block
#define PPT 2            // points per thread (1024 points / 512 threads)

__global__ __launch_bounds__(NT, 8) void vol_rot_gather(
    const float* __restrict__ vol,   // [B, C, S, S, S]
    const float* __restrict__ rot,   // [B, 3, 3]
    float* __restrict__ out)         // [B, C, S, S, S]
{
    const int tid = threadIdx.x;

    // ---- XCD-contiguous swizzle: XCD k (= blockIdx%8) gets blocks
    //      [k*256, (k+1)*256) of the logical grid = exactly batch k. ----
    const int wg = (blockIdx.x & 7) * (BB * 256 / 8) + (blockIdx.x >> 3);
    const int t  = wg & 255;
    const int b  = wg >> 8;
    const int w0 = (t & 3) * TW;
    const int h0 = ((t >> 2) & 7) * TH;
    const int d0 = (t >> 5) * TD;

    const float* R = rot + b * 9;    // wave-uniform -> scalar loads
    const float R00 = R[0], R01 = R[1], R02 = R[2];
    const float R10 = R[3], R11 = R[4], R12 = R[5];
    const float R20 = R[6], R21 = R[7], R22 = R[8];

    const float st = 2.0f / 63.0f;

    // ---- per-point precompute (shared across all 16 channels):
    //      8 tap byte-offsets (clamped) + 8 weights (validity folded) ----
    int   off[PPT][8];      // byte offset of tap k = dz*4+dy*2+dx
    int   ospat[PPT];       // output spatial index
    float wgt[PPT][8];      // trilinear weights with validity folded in
#pragma unroll
    for (int p = 0; p < PPT; ++p) {
        const int idx = tid + p * NT;
        const int pw = idx & 15, ph = (idx >> 4) & 7, pd = idx >> 7;
        const float xb = -1.0f + (float)(w0 + pw) * st;
        const float yb = -1.0f + (float)(h0 + ph) * st;
        const float zb = -1.0f + (float)(d0 + pd) * st;
        const float gx = R00 * xb + R10 * yb + R20 * zb;
        const float gy = R01 * xb + R11 * yb + R21 * zb;
        const float gz = R02 * xb + R12 * yb + R22 * zb;
        const float vx = (gx + 1.0f) * 32.0f - 0.5f;
        const float vy = (gy + 1.0f) * 32.0f - 0.5f;
        const float vz = (gz + 1.0f) * 32.0f - 0.5f;
        const float fx = floorf(vx), fy = floorf(vy), fz = floorf(vz);
        const float tx = vx - fx, ty = vy - fy, tz = vz - fz;
        const int x0 = (int)fx, y0 = (int)fy, z0 = (int)fz;

        // per-axis weights with validity folded (value*0 for OOB taps)
        const float wx0 = (1.0f - tx) * (((unsigned)x0       < 64u) ? 1.0f : 0.0f);
        const float wx1 = tx          * (((unsigned)(x0 + 1) < 64u) ? 1.0f : 0.0f);
        const float wy0 = (1.0f - ty) * (((unsigned)y0       < 64u) ? 1.0f : 0.0f);
        const float wy1 = ty          * (((unsigned)(y0 + 1) < 64u) ? 1.0f : 0.0f);
        const float wz0 = (1.0f - tz) * (((unsigned)z0       < 64u) ? 1.0f : 0.0f);
        const float wz1 = tz          * (((unsigned)(z0 + 1) < 64u) ? 1.0f : 0.0f);

        // clamped coordinates for addressing (weight is 0 when clamped)
        const int xc0 = min(max(x0,     0), 63);
        const int xc1 = min(max(x0 + 1, 0), 63);
        const int yc0 = min(max(y0,     0), 63);
        const int yc1 = min(max(y0 + 1, 0), 63);
        const int zc0 = min(max(z0,     0), 63);
        const int zc1 = min(max(z0 + 1, 0), 63);

        const int ry0b = yc0 << 6, ry1b = yc1 << 6;   // row bases (elements)
        const int pz0b = zc0 << 12, pz1b = zc1 << 12; // plane bases (elements)
        off[p][0] = (pz0b + ry0b + xc0) << 2;
        off[p][1] = (pz0b + ry0b + xc1) << 2;
        off[p][2] = (pz0b + ry1b + xc0) << 2;
        off[p][3] = (pz0b + ry1b + xc1) << 2;
        off[p][4] = (pz1b + ry0b + xc0) << 2;
        off[p][5] = (pz1b + ry0b + xc1) << 2;
        off[p][6] = (pz1b + ry1b + xc0) << 2;
        off[p][7] = (pz1b + ry1b + xc1) << 2;

        wgt[p][0] = wz0 * wy0 * wx0; wgt[p][1] = wz0 * wy0 * wx1;
        wgt[p][2] = wz0 * wy1 * wx0; wgt[p][3] = wz0 * wy1 * wx1;
        wgt[p][4] = wz1 * wy0 * wx0; wgt[p][5] = wz1 * wy0 * wx1;
        wgt[p][6] = wz1 * wy1 * wx0; wgt[p][7] = wz1 * wy1 * wx1;

        ospat[p] = ((d0 + pd) * 64 + (h0 + ph)) * 64 + (w0 + pw);
    }

    // ---- channel loop: 8 gathers + 8 FMA + 1 store per point ----
    const float* vp = vol + (size_t)b * CCH * SP;   // uniform base (SGPR)
    float*       op = out + (size_t)b * CCH * SP;

#pragma unroll 2
    for (int c = 0; c < CCH; ++c) {
        const char* vc = (const char*)vp;
#pragma unroll
        for (int p = 0; p < PPT; ++p) {
            const float v0 = *(const float*)(vc + off[p][0]);
            const float v1 = *(const float*)(vc + off[p][1]);
            const float v2 = *(const float*)(vc + off[p][2]);
            const float v3 = *(const float*)(vc + off[p][3]);
            const float v4 = *(const float*)(vc + off[p][4]);
            const float v5 = *(const float*)(vc + off[p][5]);
            const float v6 = *(const float*)(vc + off[p][6]);
            const float v7 = *(const float*)(vc + off[p][7]);
            const float acc = wgt[p][0] * v0 + wgt[p][1] * v1
                            + wgt[p][2] * v2 + wgt[p][3] * v3
                            + wgt[p][4] * v4 + wgt[p][5] * v5
                            + wgt[p][6] * v6 + wgt[p][7] * v7;
            op[ospat[p]] = acc;
        }
        vp += SP;
        op += SP;
    }
}

extern "C" void kernel_launch(void* const* d_in, const int* in_sizes, int n_in,
                              void* d_out, int out_size, void* d_ws, size_t ws_size,
                              hipStream_t stream) {
    const float* vol = (const float*)d_in[0];
    const float* rot = (const float*)d_in[1];
    float* out = (float*)d_out;

    // 8 batches x (4 x 8 x 8) tiles = 2048 blocks
    vol_rot_gather<<<dim3(BB * 256), dim3(NT), 0, stream>>>(vol, rot, out);
}

// Round 3
// 384.415 us; speedup vs baseline: 2.0635x; 2.0635x over previous
//
#include <hip/hip_runtime.h>

// VolumeRotation via LDS tiling: B=8, C=16, S=64.
// Each block handles a 16x8x8 output tile for one batch. The rotated
// bounding region of the tile (<= 8000 floats incl. slack) is staged into
// LDS per channel with ghost zeros outside the volume, then each point
// does 8 LDS reads (4x ds_read2) + trilinear weights.
//
// History:
//  R0 (208 us): LDS tiling, fixed 16 staging iterations.
//  R1 (306 us): swizzle OK (FETCH 318->119 MB) but break-guarded unroll
//               rolled the loops -> vals[]/voff[] in scratch. Reverted.
//  R2 (634 us): no-LDS direct gather -> L1-path bound, FETCH 549 MB. Refuted.
//  R3: R0 structure + XCD swizzle + guard-per-iteration dynamic staging
//      (literal indices via macros; arrays stay in registers).

#define S 64
#define SP (S * S * S)
#define CCH 16
#define BB 8

#define TW 16
#define TH 8
#define TD 8
#define NT 512           // threads per block
#define PPT 2            // points per thread (1024 points / 512 threads)
#define CAP 8192         // LDS floats capacity (worst-case region <= 8000)
#define MAXIT 16         // CAP / NT max staging iterations

__global__ __launch_bounds__(NT, 4) void vol_rot_tiled(
    const float* __restrict__ vol,   // [B, C, S, S, S]
    const float* __restrict__ rot,   // [B, 3, 3]
    float* __restrict__ out)         // [B, C, S, S, S]
{
    __shared__ float smem[CAP + 2];

    const int tid = threadIdx.x;

    // ---- XCD-contiguous swizzle: XCD k (= blockIdx%8) gets blocks
    //      [k*256, (k+1)*256) of the logical grid = exactly batch k. ----
    const int wg = (blockIdx.x & 7) * (BB * 256 / 8) + (blockIdx.x >> 3);
    const int t  = wg & 255;
    const int b  = wg >> 8;
    const int w0 = (t & 3) * TW;
    const int h0 = ((t >> 2) & 7) * TH;
    const int d0 = (t >> 5) * TD;

    const float* R = rot + b * 9;    // wave-uniform -> scalar loads
    const float R00 = R[0], R01 = R[1], R02 = R[2];
    const float R10 = R[3], R11 = R[4], R12 = R[5];
    const float R20 = R[6], R21 = R[7], R22 = R[8];

    const float st = 2.0f / 63.0f;

    // ---- bounding box of the tile's sample positions (affine -> corners) ----
    float xmn = 1e30f, xmx = -1e30f;
    float ymn = 1e30f, ymx = -1e30f;
    float zmn = 1e30f, zmx = -1e30f;
#pragma unroll
    for (int k = 0; k < 8; ++k) {
        const float xb = -1.0f + (float)(w0 + ((k & 1) ? (TW - 1) : 0)) * st;
        const float yb = -1.0f + (float)(h0 + ((k & 2) ? (TH - 1) : 0)) * st;
        const float zb = -1.0f + (float)(d0 + ((k & 4) ? (TD - 1) : 0)) * st;
        const float gx = R00 * xb + R10 * yb + R20 * zb;
        const float gy = R01 * xb + R11 * yb + R21 * zb;
        const float gz = R02 * xb + R12 * yb + R22 * zb;
        const float vx = (gx + 1.0f) * 32.0f - 0.5f;
        const float vy = (gy + 1.0f) * 32.0f - 0.5f;
        const float vz = (gz + 1.0f) * 32.0f - 0.5f;
        xmn = fminf(xmn, vx); xmx = fmaxf(xmx, vx);
        ymn = fminf(ymn, vy); ymx = fmaxf(ymx, vy);
        zmn = fminf(zmn, vz); zmx = fmaxf(zmx, vz);
    }
    const int rx0 = (int)floorf(xmn);
    const int ry0 = (int)floorf(ymn);
    const int rz0 = (int)floorf(zmn);
    int ex = (int)floorf(xmx) + 2 - rx0;   // region extents (>=2, <=21)
    int ey = (int)floorf(ymx) + 2 - ry0;
    int ez = (int)floorf(zmx) + 2 - rz0;
    if (ex * ey * ez > CAP) ez = CAP / (ex * ey);   // safety (unreachable)

    const int plane = ex * ey;
    const int rsz   = plane * ez;              // actual region size (<= CAP)
    const int nit   = (rsz + NT - 1) >> 9;     // staging iterations needed (1..16)
    const float invp = 1.0f / (float)plane;
    const float inve = 1.0f / (float)ex;

    // ---- staging address precompute (shared across all 16 channels) ----
    // Guard-per-iteration with LITERAL indices: arrays stay in registers
    // (no break inside unroll -> no rolled loop -> no scratch).
    int voff[MAXIT];        // byte offset into one channel's volume (clamped)
    unsigned mask = 0;      // bit i: coordinate inside volume
#define STAGE_ADDR(i)                                                         \
    if (nit > (i)) {                                                          \
        const int r  = tid + (i) * NT;                                        \
        const int rz = (int)(((float)r + 0.5f) * invp);                       \
        const int rm = r - rz * plane;                                        \
        const int ry = (int)(((float)rm + 0.5f) * inve);                      \
        const int rx = rm - ry * ex;                                          \
        const int gx = rx0 + rx, gy = ry0 + ry, gz = rz0 + rz;                \
        const bool valid = ((unsigned)gx < 64u) & ((unsigned)gy < 64u)        \
                         & ((unsigned)gz < 64u);                              \
        const int gxc = min(max(gx, 0), 63);                                  \
        const int gyc = min(max(gy, 0), 63);                                  \
        const int gzc = min(max(gz, 0), 63);                                  \
        voff[i] = (((((gzc << 6) + gyc) << 6) + gxc) << 2);                   \
        mask |= ((unsigned)valid) << (i);                                     \
    }
    STAGE_ADDR(0)  STAGE_ADDR(1)  STAGE_ADDR(2)  STAGE_ADDR(3)
    STAGE_ADDR(4)  STAGE_ADDR(5)  STAGE_ADDR(6)  STAGE_ADDR(7)
    STAGE_ADDR(8)  STAGE_ADDR(9)  STAGE_ADDR(10) STAGE_ADDR(11)
    STAGE_ADDR(12) STAGE_ADDR(13) STAGE_ADDR(14) STAGE_ADDR(15)
#undef STAGE_ADDR

    // ---- per-point state (shared across channels) ----
    int   obase[PPT];       // LDS byte offset of (z0,y0,x0) corner
    int   ospat[PPT];       // output spatial index
    float wgt[PPT][8];      // trilinear weights, k = dz*4+dy*2+dx
#pragma unroll
    for (int p = 0; p < PPT; ++p) {
        const int idx = tid + p * NT;
        const int pw = idx & 15, ph = (idx >> 4) & 7, pd = idx >> 7;
        const float xb = -1.0f + (float)(w0 + pw) * st;
        const float yb = -1.0f + (float)(h0 + ph) * st;
        const float zb = -1.0f + (float)(d0 + pd) * st;
        const float gx = R00 * xb + R10 * yb + R20 * zb;
        const float gy = R01 * xb + R11 * yb + R21 * zb;
        const float gz = R02 * xb + R12 * yb + R22 * zb;
        const float vx = (gx + 1.0f) * 32.0f - 0.5f;
        const float vy = (gy + 1.0f) * 32.0f - 0.5f;
        const float vz = (gz + 1.0f) * 32.0f - 0.5f;
        const float fx = floorf(vx), fy = floorf(vy), fz = floorf(vz);
        const float tx = vx - fx, ty = vy - fy, tz = vz - fz;
        int lx = (int)fx - rx0, ly = (int)fy - ry0, lz = (int)fz - rz0;
        lx = min(max(lx, 0), ex - 2);   // clamp only engages when weight==0
        ly = min(max(ly, 0), ey - 2);   // or ~1e-5 (fp rounding at edges)
        lz = min(max(lz, 0), ez - 2);
        obase[p] = ((lz * ey + ly) * ex + lx) * 4;
        ospat[p] = ((d0 + pd) * 64 + (h0 + ph)) * 64 + (w0 + pw);
        const float ux = 1.0f - tx, uy = 1.0f - ty, uz = 1.0f - tz;
        wgt[p][0] = uz * uy * ux; wgt[p][1] = uz * uy * tx;
        wgt[p][2] = uz * ty * ux; wgt[p][3] = uz * ty * tx;
        wgt[p][4] = tz * uy * ux; wgt[p][5] = tz * uy * tx;
        wgt[p][6] = tz * ty * ux; wgt[p][7] = tz * ty * tx;
    }

    // ---- channel loop: stage region -> LDS, then sample ----
    const char* smemb = (const char*)smem;
    const int dy4 = ex * 4;
    const int dz4 = plane * 4;
    const float* volb = vol + (size_t)b * CCH * SP;
    float*       outb = out + (size_t)b * CCH * SP;

    float vals[MAXIT];
#define PREFETCH(i, vc)                                                       \
    if (nit > (i)) vals[i] = *(const float*)((vc) + voff[i]);
#define LDS_WRITE(i)                                                          \
    if (nit > (i))                                                            \
        smem[tid + (i) * NT] = ((mask >> (i)) & 1u) ? vals[i] : 0.0f;

    // prefetch channel 0 (only the needed iterations)
    {
        const char* vc = (const char*)volb;
        PREFETCH(0, vc)  PREFETCH(1, vc)  PREFETCH(2, vc)  PREFETCH(3, vc)
        PREFETCH(4, vc)  PREFETCH(5, vc)  PREFETCH(6, vc)  PREFETCH(7, vc)
        PREFETCH(8, vc)  PREFETCH(9, vc)  PREFETCH(10, vc) PREFETCH(11, vc)
        PREFETCH(12, vc) PREFETCH(13, vc) PREFETCH(14, vc) PREFETCH(15, vc)
    }

    for (int c = 0; c < CCH; ++c) {
        __syncthreads();    // previous channel's sampling done
        LDS_WRITE(0)  LDS_WRITE(1)  LDS_WRITE(2)  LDS_WRITE(3)
        LDS_WRITE(4)  LDS_WRITE(5)  LDS_WRITE(6)  LDS_WRITE(7)
        LDS_WRITE(8)  LDS_WRITE(9)  LDS_WRITE(10) LDS_WRITE(11)
        LDS_WRITE(12) LDS_WRITE(13) LDS_WRITE(14) LDS_WRITE(15)
        __syncthreads();    // region visible

        // prefetch next channel's region (overlaps with sampling below)
        if (c + 1 < CCH) {
            const char* vc = (const char*)(volb + (c + 1) * SP);
            PREFETCH(0, vc)  PREFETCH(1, vc)  PREFETCH(2, vc)  PREFETCH(3, vc)
            PREFETCH(4, vc)  PREFETCH(5, vc)  PREFETCH(6, vc)  PREFETCH(7, vc)
            PREFETCH(8, vc)  PREFETCH(9, vc)  PREFETCH(10, vc) PREFETCH(11, vc)
            PREFETCH(12, vc) PREFETCH(13, vc) PREFETCH(14, vc) PREFETCH(15, vc)
        }

#pragma unroll
        for (int p = 0; p < PPT; ++p) {
            const char* pb = smemb + obase[p];
            const float v000 = *(const float*)(pb);
            const float v001 = *(const float*)(pb + 4);
            const float v010 = *(const float*)(pb + dy4);
            const float v011 = *(const float*)(pb + dy4 + 4);
            const float v100 = *(const float*)(pb + dz4);
            const float v101 = *(const float*)(pb + dz4 + 4);
            const float v110 = *(const float*)(pb + dz4 + dy4);
            const float v111 = *(const float*)(pb + dz4 + dy4 + 4);
            const float acc = wgt[p][0] * v000 + wgt[p][1] * v001
                            + wgt[p][2] * v010 + wgt[p][3] * v011
                            + wgt[p][4] * v100 + wgt[p][5] * v101
                            + wgt[p][6] * v110 + wgt[p][7] * v111;
            outb[c * SP + ospat[p]] = acc;
        }
    }
#undef PREFETCH
#undef LDS_WRITE
}

extern "C" void kernel_launch(void* const* d_in, const int* in_sizes, int n_in,
                              void* d_out, int out_size, void* d_ws, size_t ws_size,
                              hipStream_t stream) {
    const float* vol = (const float*)d_in[0];
    const float* rot = (const float*)d_in[1];
    float* out = (float*)d_out;

    // 8 batches x (4 x 8 x 8) tiles = 2048 blocks
    vol_rot_tiled<<<dim3(BB * 256), dim3(NT), 0, stream>>>(vol, rot, out);
}

// Round 4
// 376.325 us; speedup vs baseline: 2.1079x; 1.0215x over previous
//
#include <hip/hip_runtime.h>

// VolumeRotation via double-buffered LDS tiling: B=8, C=16, S=64.
//
// History:
//  R0 (208 us): LDS tiling 16x8x8 tile, fixed 16 staging iters, 2 barriers/ch.
//  R1 (306 us): swizzle OK (FETCH 318->119 MB) but break-guarded unroll
//               rolled loops -> scratch. Reverted.
//  R2 (634 us): no-LDS direct gather -> L1-path bound, FETCH 549 MB. Refuted.
//  R3 (213 us): dynamic staging in regs (3x less staging work) -> FLAT.
//               Staging issue rate is NOT the bottleneck.
//  R4: latency-hiding restructure. Key insight: __launch_bounds__ 2nd arg
//      is waves/EU, so (512,4) capped the kernel at 2 blocks/CU (matches
//      observed 33-40% occupancy) -> every barrier stalled half the CU.
//      - __launch_bounds__(512,8): 4 blocks/CU target.
//      - 8^3 tile: worst-case region <= (7.11*sqrt(3)+3)^3 ~ 3600 floats
//        (l1-norm of rotation columns <= sqrt(3)); two 4608-float buffers
//        = 36 KB -> 4 blocks/CU by LDS as well.
//      - Double-buffered LDS: ONE barrier per channel; ds_writes of ch c+1
//        overlap sampling of ch c.
//      - 2-deep register prefetch (valsA/valsB ping-pong, unroll-by-2 so
//        all array indices are literal): loads for c+2 issued a full phase
//        before their ds_write -> vmcnt wait ~ 0.

#define S 64
#define SP (S * S * S)
#define CCH 16
#define BB 8

#define TS 8             // cubic tile edge: 8x8x8 = 512 points
#define NT 512           // threads per block; 1 point per thread
#define TPB 512          // tiles per batch = (64/8)^3
#define HALF 4608        // floats per LDS buffer (worst-case region ~3600)
#define MAXIT 9          // ceil(HALF / NT)

__global__ __launch_bounds__(NT, 8) void vol_rot_dbuf(
    const float* __restrict__ vol,   // [B, C, S, S, S]
    const float* __restrict__ rot,   // [B, 3, 3]
    float* __restrict__ out)         // [B, C, S, S, S]
{
    __shared__ float smem[2 * HALF];

    const int tid = threadIdx.x;

    // ---- XCD-contiguous swizzle: 4096 blocks; XCD k (= blockIdx%8) gets
    //      wg in [k*512,(k+1)*512) = exactly batch k. ----
    const int wg = (blockIdx.x & 7) * TPB + (blockIdx.x >> 3);
    const int t  = wg & (TPB - 1);
    const int b  = wg >> 9;
    const int w0 = (t & 7) << 3;
    const int h0 = ((t >> 3) & 7) << 3;
    const int d0 = (t >> 6) << 3;

    const float* R = rot + b * 9;    // wave-uniform -> scalar loads
    const float R00 = R[0], R01 = R[1], R02 = R[2];
    const float R10 = R[3], R11 = R[4], R12 = R[5];
    const float R20 = R[6], R21 = R[7], R22 = R[8];

    const float st = 2.0f / 63.0f;

    // ---- bounding box of the tile's sample positions (affine -> corners) ----
    float xmn = 1e30f, xmx = -1e30f;
    float ymn = 1e30f, ymx = -1e30f;
    float zmn = 1e30f, zmx = -1e30f;
#pragma unroll
    for (int k = 0; k < 8; ++k) {
        const float xb = -1.0f + (float)(w0 + ((k & 1) ? (TS - 1) : 0)) * st;
        const float yb = -1.0f + (float)(h0 + ((k & 2) ? (TS - 1) : 0)) * st;
        const float zb = -1.0f + (float)(d0 + ((k & 4) ? (TS - 1) : 0)) * st;
        const float gx = R00 * xb + R10 * yb + R20 * zb;
        const float gy = R01 * xb + R11 * yb + R21 * zb;
        const float gz = R02 * xb + R12 * yb + R22 * zb;
        const float vx = (gx + 1.0f) * 32.0f - 0.5f;
        const float vy = (gy + 1.0f) * 32.0f - 0.5f;
        const float vz = (gz + 1.0f) * 32.0f - 0.5f;
        xmn = fminf(xmn, vx); xmx = fmaxf(xmx, vx);
        ymn = fminf(ymn, vy); ymx = fmaxf(ymx, vy);
        zmn = fminf(zmn, vz); zmx = fmaxf(zmx, vz);
    }
    const int rx0 = (int)floorf(xmn);
    const int ry0 = (int)floorf(ymn);
    const int rz0 = (int)floorf(zmn);
    int ex = (int)floorf(xmx) + 2 - rx0;   // region extents (>=2, <=~17)
    int ey = (int)floorf(ymx) + 2 - ry0;
    int ez = (int)floorf(zmx) + 2 - rz0;
    if (ex * ey * ez > HALF) ez = HALF / (ex * ey);   // safety (unreachable)

    const int plane = ex * ey;
    const int rsz   = plane * ez;              // actual region size (<= HALF)
    const int nit   = (rsz + NT - 1) >> 9;     // staging iterations (1..9)
    const float invp = 1.0f / (float)plane;
    const float inve = 1.0f / (float)ex;

    // ---- staging address precompute (shared across all 16 channels) ----
    // Guard-per-iteration with LITERAL indices: arrays stay in registers.
    int voff[MAXIT];        // byte offset into one channel's volume (clamped)
    unsigned mask = 0;      // bit i: coordinate inside volume
#define STAGE_ADDR(i)                                                         \
    if (nit > (i)) {                                                          \
        const int r  = tid + (i) * NT;                                        \
        const int rz = (int)(((float)r + 0.5f) * invp);                       \
        const int rm = r - rz * plane;                                        \
        const int ry = (int)(((float)rm + 0.5f) * inve);                      \
        const int rx = rm - ry * ex;                                          \
        const int gx = rx0 + rx, gy = ry0 + ry, gz = rz0 + rz;                \
        const bool valid = ((unsigned)gx < 64u) & ((unsigned)gy < 64u)        \
                         & ((unsigned)gz < 64u);                              \
        const int gxc = min(max(gx, 0), 63);                                  \
        const int gyc = min(max(gy, 0), 63);                                  \
        const int gzc = min(max(gz, 0), 63);                                  \
        voff[i] = (((((gzc << 6) + gyc) << 6) + gxc) << 2);                   \
        mask |= ((unsigned)valid) << (i);                                     \
    }
    STAGE_ADDR(0) STAGE_ADDR(1) STAGE_ADDR(2) STAGE_ADDR(3) STAGE_ADDR(4)
    STAGE_ADDR(5) STAGE_ADDR(6) STAGE_ADDR(7) STAGE_ADDR(8)
#undef STAGE_ADDR

    // ---- per-point state (1 point per thread, shared across channels) ----
    int   obase;            // LDS byte offset of (z0,y0,x0) corner (buffer-rel)
    int   ospat;            // output spatial index
    float wgt[8];           // trilinear weights, k = dz*4+dy*2+dx
    {
        const int pw = tid & 7, ph = (tid >> 3) & 7, pd = tid >> 6;
        const float xb = -1.0f + (float)(w0 + pw) * st;
        const float yb = -1.0f + (float)(h0 + ph) * st;
        const float zb = -1.0f + (float)(d0 + pd) * st;
        const float gx = R00 * xb + R10 * yb + R20 * zb;
        const float gy = R01 * xb + R11 * yb + R21 * zb;
        const float gz = R02 * xb + R12 * yb + R22 * zb;
        const float vx = (gx + 1.0f) * 32.0f - 0.5f;
        const float vy = (gy + 1.0f) * 32.0f - 0.5f;
        const float vz = (gz + 1.0f) * 32.0f - 0.5f;
        const float fx = floorf(vx), fy = floorf(vy), fz = floorf(vz);
        const float tx = vx - fx, ty = vy - fy, tz = vz - fz;
        int lx = (int)fx - rx0, ly = (int)fy - ry0, lz = (int)fz - rz0;
        lx = min(max(lx, 0), ex - 2);   // clamp only engages when weight==0
        ly = min(max(ly, 0), ey - 2);   // or ~1e-5 (fp rounding at edges)
        lz = min(max(lz, 0), ez - 2);
        obase = ((lz * ey + ly) * ex + lx) * 4;
        ospat = ((d0 + pd) * 64 + (h0 + ph)) * 64 + (w0 + pw);
        const float ux = 1.0f - tx, uy = 1.0f - ty, uz = 1.0f - tz;
        wgt[0] = uz * uy * ux; wgt[1] = uz * uy * tx;
        wgt[2] = uz * ty * ux; wgt[3] = uz * ty * tx;
        wgt[4] = tz * uy * ux; wgt[5] = tz * uy * tx;
        wgt[6] = tz * ty * ux; wgt[7] = tz * ty * tx;
    }

    const char* smemb = (const char*)smem;
    const int dy4 = ex * 4;
    const int dz4 = plane * 4;
    const float* volb = vol + (size_t)b * CCH * SP;
    float*       outb = out + (size_t)b * CCH * SP;

    float valsA[MAXIT], valsB[MAXIT];

#define PREF(i, vc, ARR)                                                      \
    if (nit > (i)) ARR[i] = *(const float*)((vc) + voff[i]);
#define PREF9(vc, ARR)                                                        \
    PREF(0, vc, ARR) PREF(1, vc, ARR) PREF(2, vc, ARR) PREF(3, vc, ARR)       \
    PREF(4, vc, ARR) PREF(5, vc, ARR) PREF(6, vc, ARR) PREF(7, vc, ARR)       \
    PREF(8, vc, ARR)
#define WRT(i, ARR, SB)                                                       \
    if (nit > (i))                                                            \
        smem[(SB) + tid + (i) * NT] = ((mask >> (i)) & 1u) ? ARR[i] : 0.0f;
#define WRT9(ARR, SB)                                                         \
    WRT(0, ARR, SB) WRT(1, ARR, SB) WRT(2, ARR, SB) WRT(3, ARR, SB)           \
    WRT(4, ARR, SB) WRT(5, ARR, SB) WRT(6, ARR, SB) WRT(7, ARR, SB)           \
    WRT(8, ARR, SB)

    // ---- prologue: region 0 -> buf0; region 1 -> valsB ----
    {
        const char* vc = (const char*)volb;
        PREF9(vc, valsA)
    }
    WRT9(valsA, 0)
    {
        const char* vc = (const char*)(volb + SP);
        PREF9(vc, valsB)
    }
    __syncthreads();

    // ---- channel loop: one barrier per channel; phase c:
    //      issue loads region(c+2) / write region(c+1) / sample region(c) ----
#define PHASE(cval, LD_ARR, WR_ARR, SB_WR, SB_SMP)                            \
    {                                                                         \
        const int c = (cval);                                                 \
        if (c + 2 < CCH) {                                                    \
            const char* vc = (const char*)(volb + (size_t)(c + 2) * SP);      \
            PREF9(vc, LD_ARR)                                                 \
        }                                                                     \
        if (c + 1 < CCH) { WRT9(WR_ARR, SB_WR) }                              \
        {                                                                     \
            const char* pb = smemb + (SB_SMP) * 4 + obase;                    \
            const float v000 = *(const float*)(pb);                          \
            const float v001 = *(const float*)(pb + 4);                      \
            const float v010 = *(const float*)(pb + dy4);                    \
            const float v011 = *(const float*)(pb + dy4 + 4);                \
            const float v100 = *(const float*)(pb + dz4);                    \
            const float v101 = *(const float*)(pb + dz4 + 4);                \
            const float v110 = *(const float*)(pb + dz4 + dy4);              \
            const float v111 = *(const float*)(pb + dz4 + dy4 + 4);          \
            const float acc = wgt[0] * v000 + wgt[1] * v001                   \
                            + wgt[2] * v010 + wgt[3] * v011                   \
                            + wgt[4] * v100 + wgt[5] * v101                   \
                            + wgt[6] * v110 + wgt[7] * v111;                  \
            outb[c * SP + ospat] = acc;                                       \
        }                                                                     \
        __syncthreads();                                                      \
    }

    for (int c2 = 0; c2 < CCH; c2 += 2) {
        PHASE(c2,     valsA, valsB, HALF, 0)      // sample buf0, write buf1
        PHASE(c2 + 1, valsB, valsA, 0,    HALF)   // sample buf1, write buf0
    }
#undef PHASE
#undef WRT9
#undef WRT
#undef PREF9
#undef PREF
}

extern "C" void kernel_launch(void* const* d_in, const int* in_sizes, int n_in,
                              void* d_out, int out_size, void* d_ws, size_t ws_size,
                              hipStream_t stream) {
    const float* vol = (const float*)d_in[0];
    const float* rot = (const float*)d_in[1];
    float* out = (float*)d_out;

    // 8 batches x 512 tiles (8^3 each) = 4096 blocks
    vol_rot_dbuf<<<dim3(BB * TPB), dim3(NT), 0, stream>>>(vol, rot, out);
}